// Round 7
// baseline (946.024 us; speedup 1.0000x reference)
//
#include <hip/hip_runtime.h>
#include <stdint.h>

#define NB 8
#define NP 4096
#define NS 1024
#define NK 64
#define ND 64
#define NH 64
#define NCO 128

#define FPS_T 512
#define PPT (NP / FPS_T)   // 8 points per thread

// padded K strides (in halves) for conflict-free b128 LDS access
#define K1P 104            // layer1 K: 64 x-ch + 3 xyz + zeros to 96, padded to 104
#define K2P 72             // layer2/3 K: 64, padded to 72

#define QPB 16             // queries per block in mlp_kernel

// workspace layout (bytes)
#define WS_SPS  0                    // float4[NB][NP] sorted points  = 512 KB
#define WS_BIDX 524288               // short[NB*NS][NK] ball idx     = 1 MB
#define WS_WT   1572864              // _Float16 wt                   = 40 KB

typedef _Float16 half8v __attribute__((ext_vector_type(8)));
typedef _Float16 half4v __attribute__((ext_vector_type(4)));
typedef _Float16 half2v __attribute__((ext_vector_type(2)));
typedef float    floatx4 __attribute__((ext_vector_type(4)));

// DPP move helper (ctrl must be compile-time constant)
template <int CTRL>
__device__ __forceinline__ float dpp_mov_f32(float x) {
    return __int_as_float(__builtin_amdgcn_update_dpp(
        0, __float_as_int(x), CTRL, 0xf, 0xf, true));
}

// u64 max with DPP-shifted partner (bound_ctrl zero-fill; keys >= 0 so 0 is identity)
template <int CTRL>
__device__ __forceinline__ unsigned long long dpp_max_u64(unsigned long long k) {
    unsigned lo = (unsigned)k, hi = (unsigned)(k >> 32);
    unsigned olo = (unsigned)__builtin_amdgcn_update_dpp(0, (int)lo, CTRL, 0xf, 0xf, true);
    unsigned ohi = (unsigned)__builtin_amdgcn_update_dpp(0, (int)hi, CTRL, 0xf, 0xf, true);
    unsigned long long o = ((unsigned long long)ohi << 32) | olo;
    return (o > k) ? o : k;
}

// ---------------- Kernel 0a: weight transpose + f16 convert ----------------
__global__ __launch_bounds__(64) void wt_kernel(const float* __restrict__ W1,
                                                const float* __restrict__ W2,
                                                const float* __restrict__ W3,
                                                _Float16* __restrict__ wt)
{
    const int j = blockIdx.x;
    const int t = threadIdx.x;
    if (j < 64) {
        for (int k = t; k < K1P; k += 64) {
            float v = 0.f;
            if (k < 64)       v = W1[(3 + k) * 64 + j];
            else if (k < 67)  v = W1[(k - 64) * 64 + j];
            wt[j * K1P + k] = (_Float16)v;
        }
    } else if (j < 128) {
        const int r = j - 64;
        for (int k = t; k < K2P; k += 64) {
            float v = (k < 64) ? W2[k * 64 + r] : 0.f;
            wt[6656 + r * K2P + k] = (_Float16)v;
        }
    } else {
        const int r = j - 128;
        for (int k = t; k < K2P; k += 64) {
            float v = (k < 64) ? W3[k * 128 + r] : 0.f;
            wt[11264 + r * K2P + k] = (_Float16)v;
        }
    }
}

// ---------------- Kernel 0b: spatial counting sort (8x8x8 Morton cells) ------
// One block per batch. Output sps[b][slot] = {x,y,z, bits(orig_idx)} in
// Morton-cell order. Order within a cell is arbitrary (argmax ties use
// orig_idx, not storage order).
__global__ __launch_bounds__(512) void sort_kernel(const float* __restrict__ pos,
                                                   float4* __restrict__ sps)
{
    const int b   = blockIdx.x;
    const int tid = threadIdx.x;
    __shared__ int hist[512];
    __shared__ int off[512];
    __shared__ short cellof[NP];

    const float* p = pos + (size_t)b * NP * 3;
    if (tid < 512) hist[tid] = 0;
    __syncthreads();

    for (int i = tid; i < NP; i += 512) {
        float x = p[3 * i], y = p[3 * i + 1], z = p[3 * i + 2];
        int cx = min(7, max(0, (int)(x * 8.f)));
        int cy = min(7, max(0, (int)(y * 8.f)));
        int cz = min(7, max(0, (int)(z * 8.f)));
        int m = 0;
#pragma unroll
        for (int bb = 0; bb < 3; ++bb)
            m |= ((cx >> bb & 1) << (3 * bb)) |
                 ((cy >> bb & 1) << (3 * bb + 1)) |
                 ((cz >> bb & 1) << (3 * bb + 2));
        cellof[i] = (short)m;
        atomicAdd(&hist[m], 1);
    }
    __syncthreads();

    if (tid < 64) {   // exclusive scan of 512 bins: 8 serial/lane + wave scan
        const int base = tid * 8;
        int sums[8]; int run = 0;
#pragma unroll
        for (int k = 0; k < 8; ++k) { sums[k] = run; run += hist[base + k]; }
        int v = run;
        for (int d = 1; d < 64; d <<= 1) {
            int o = __shfl_up(v, d);
            if (tid >= d) v += o;
        }
        const int excl = v - run;
#pragma unroll
        for (int k = 0; k < 8; ++k) off[base + k] = excl + sums[k];
    }
    __syncthreads();

    for (int i = tid; i < NP; i += 512) {
        int m = (int)cellof[i];
        int slot = atomicAdd(&off[m], 1);
        sps[(size_t)b * NP + slot] =
            make_float4(p[3 * i], p[3 * i + 1], p[3 * i + 2], __int_as_float(i));
    }
}

// ---------------- Kernel 1: farthest point sampling with bbox pruning -------
// One block per batch, 512 threads, 8 spatially-sorted points/thread.
// Bit-exact fp32 (contract off). Per step: each lane tests its 8-point bbox
// against the influence ball (d2_lb < lmax, RN-monotone => conservative);
// a wave with no lane in range skips the whole update and replays its cached
// wave key. Updating waves: exact min-update + argmax, u64-DPP wave reduce on
// key (md:32 | ~orig_idx:12 | sorted_pos:12) — exact first-index tie-breaks.
// Cross-wave: parity-double-buffered kbuf + proven 8-key tree; winner coords
// via broadcast sp[pos] b128 read.
__global__ __launch_bounds__(FPS_T) void fps_kernel(const float* __restrict__ pos,
                                                    const float4* __restrict__ sps,
                                                    float* __restrict__ new_xyz)
{
#pragma clang fp contract(off)
    const int b    = blockIdx.x;
    const int tid  = threadIdx.x;
    const int lane = tid & 63;
    const int wv   = tid >> 6;            // 0..7

    __shared__ float4 sp[NP];             // sorted {x,y,z,idx} per point, 64 KB
    __shared__ alignas(16) unsigned long long kbuf[2][8];

    const float4* ps = sps + (size_t)b * NP;
    for (int i = tid; i < NP; i += FPS_T) sp[i] = ps[i];
    __syncthreads();

    float px[PPT], py[PPT], pz[PPT], md[PPT];
    int   oi[PPT];
#pragma unroll
    for (int j = 0; j < PPT; ++j) {
        float4 v = sp[tid * PPT + j];
        px[j] = v.x; py[j] = v.y; pz[j] = v.z;
        oi[j] = __float_as_int(v.w);
        md[j] = 1e10f;
    }
    // per-thread bbox of its 8 points
    float bnx = px[0], bxx = px[0], bny = py[0], bxy = py[0], bnz = pz[0], bxz = pz[0];
#pragma unroll
    for (int j = 1; j < PPT; ++j) {
        bnx = fminf(bnx, px[j]); bxx = fmaxf(bxx, px[j]);
        bny = fminf(bny, py[j]); bxy = fmaxf(bxy, py[j]);
        bnz = fminf(bnz, pz[j]); bxz = fmaxf(bxz, pz[j]);
    }
    float lmax = 1e10f;
    unsigned long long ck = 0;            // cached wave key (valid after 1st update)

    // step 0: ORIGINAL point 0 (broadcast global read)
    const float* p0 = pos + (size_t)b * NP * 3;
    float lx = p0[0], ly = p0[1], lz = p0[2];
    if (tid == 0) {
        float* o = new_xyz + (size_t)b * NS * 3;
        o[0] = lx; o[1] = ly; o[2] = lz;
    }

    int par = 0;
    for (int s = 1; s < NS; ++s) {
        // conservative lower bound: dist2(last, bbox)
        float cx = fminf(fmaxf(lx, bnx), bxx);
        float cy = fminf(fmaxf(ly, bny), bxy);
        float cz = fminf(fmaxf(lz, bnz), bxz);
        float ex = lx - cx, ey = ly - cy, ez = lz - cz;
        float dlb = ex * ex + ey * ey + ez * ez;
        bool need = dlb < lmax;

        if (__ballot(need)) {
            float bv = 0.0f;
            int   boi = oi[0];
            int   bpp = tid * PPT;
#pragma unroll
            for (int j = 0; j < PPT; ++j) {
                float dx = px[j] - lx;
                float dy = py[j] - ly;
                float dz = pz[j] - lz;
                float d2 = dx * dx + dy * dy + dz * dz;   // contract(off): exact
                float m  = (md[j] < d2) ? md[j] : d2;     // jnp.minimum
                md[j] = m;
                if (m > bv) { bv = m; boi = oi[j]; bpp = tid * PPT + j; }
            }
            lmax = fmaxf(fmaxf(fmaxf(md[0], md[1]), fmaxf(md[2], md[3])),
                         fmaxf(fmaxf(md[4], md[5]), fmaxf(md[6], md[7])));
            // key: value | ~orig_idx (first-index ties) | sorted pos (lookup)
            unsigned long long k =
                ((unsigned long long)__float_as_uint(bv) << 32) |
                ((unsigned long long)((~(unsigned)boi) & 0xFFFu) << 12) |
                (unsigned long long)(unsigned)bpp;
            k = dpp_max_u64<0x111>(k);    // row_shr:1
            k = dpp_max_u64<0x112>(k);    // row_shr:2
            k = dpp_max_u64<0x114>(k);    // row_shr:4
            k = dpp_max_u64<0x118>(k);    // row_shr:8
            k = dpp_max_u64<0x142>(k);    // row_bcast:15
            k = dpp_max_u64<0x143>(k);    // row_bcast:31
            unsigned rlo = (unsigned)__builtin_amdgcn_readlane((int)(unsigned)k, 63);
            unsigned rhi = (unsigned)__builtin_amdgcn_readlane((int)(k >> 32), 63);
            ck = ((unsigned long long)rhi << 32) | rlo;
        }
        if (lane == 0) kbuf[par][wv] = ck;
        __syncthreads();

        // 8-key tree (redundant per thread, broadcast b128 reads)
        const ulonglong2* kb = (const ulonglong2*)kbuf[par];
        ulonglong2 q0 = kb[0], q1 = kb[1], q2 = kb[2], q3 = kb[3];
        unsigned long long a0 = (q0.y > q0.x) ? q0.y : q0.x;
        unsigned long long a1 = (q1.y > q1.x) ? q1.y : q1.x;
        unsigned long long a2 = (q2.y > q2.x) ? q2.y : q2.x;
        unsigned long long a3 = (q3.y > q3.x) ? q3.y : q3.x;
        unsigned long long b0 = (a1 > a0) ? a1 : a0;
        unsigned long long b1 = (a3 > a2) ? a3 : a2;
        unsigned long long g  = (b1 > b0) ? b1 : b0;

        const int pp = (int)(g & 0xFFFull);   // sorted position of winner
        float4 v = sp[pp];                     // broadcast read
        lx = v.x; ly = v.y; lz = v.z;
        if (tid == 0) {
            float* o = new_xyz + ((size_t)b * NS + s) * 3;
            o[0] = lx; o[1] = ly; o[2] = lz;
        }
        par ^= 1;
    }
}

// ---------------- Kernel 2: ball query (int16 output) ----------------
__global__ __launch_bounds__(256) void ballq_kernel(const float* __restrict__ pos,
                                                    const float* __restrict__ new_xyz,
                                                    short* __restrict__ ball_idx)
{
#pragma clang fp contract(off)
    const int lane = threadIdx.x & 63;
    const int q    = (blockIdx.x * 256 + threadIdx.x) >> 6;   // 0..NB*NS-1
    const int b    = q >> 10;

    const float* p  = pos + (size_t)b * NP * 3;
    const float  qx = new_xyz[q * 3 + 0];
    const float  qy = new_xyz[q * 3 + 1];
    const float  qz = new_xyz[q * 3 + 2];
    short* outp = ball_idx + (size_t)q * NK;

    int cnt = 0;
    for (int n0 = 0; n0 < NP; n0 += 64) {
        const int n = n0 + lane;
        float dx = qx - p[n * 3 + 0];
        float dy = qy - p[n * 3 + 1];
        float dz = qz - p[n * 3 + 2];
        float d2 = dx * dx + dy * dy + dz * dz;   // contract(off)
        bool within = d2 < 0.04f;                 // r^2, strict <
        unsigned long long m = __ballot(within);
        if (within) {
            int slot = cnt + __popcll(m & ((1ull << lane) - 1ull));
            if (slot < NK) outp[slot] = (short)n;
        }
        cnt += (int)__popcll(m);
        if (cnt >= NK) break;
    }
    if (cnt < NK) {
        if (lane < NK - cnt) outp[cnt + lane] = (short)-1;
    }
}

// ---------------- Kernel 3: persistent gather + f16-MFMA MLP + max-pool ------
__global__ __launch_bounds__(256, 2) void mlp_kernel(const float* __restrict__ x,
        const float* __restrict__ pos,
        const float* __restrict__ b1, const float* __restrict__ b2,
        const float* __restrict__ b3,
        const float* __restrict__ new_xyz, const short* __restrict__ ball_idx,
        const _Float16* __restrict__ wt,
        float* __restrict__ out)
{
    const int tid  = threadIdx.x;
    const int lane = tid & 63;
    const int wv   = tid >> 6;
    const int qd   = lane >> 4;       // quad
    const int c    = lane & 15;       // col within MFMA tile
    const int myrow = wv * 16 + c;    // this lane's neighbor row

    __shared__ alignas(16) _Float16 G [64 * K1P];   // gathered input: [nbr][k]
    __shared__ alignas(16) _Float16 H1[64 * K2P];   // h1: [nbr][ch]
    __shared__ alignas(16) _Float16 H2[64 * K2P];   // h2: [nbr][ch]
    __shared__ alignas(16) float    CW[4 * NCO];    // per-wave pooled partials
    __shared__ alignas(16) float    Lb[128];        // b1|b2 staged
    __shared__ short nbr_s[NK];

    // ---- hoist all weight fragments into registers (once per block) ----
    half8v a1[3][4], a2[2][4], a3[2][8];
#pragma unroll
    for (int ks = 0; ks < 3; ++ks)
#pragma unroll
        for (int mt = 0; mt < 4; ++mt)
            a1[ks][mt] = *(const half8v*)&wt[(mt * 16 + c) * K1P + ks * 32 + qd * 8];
#pragma unroll
    for (int ks = 0; ks < 2; ++ks)
#pragma unroll
        for (int mt = 0; mt < 4; ++mt)
            a2[ks][mt] = *(const half8v*)&wt[6656 + (mt * 16 + c) * K2P + ks * 32 + qd * 8];
#pragma unroll
    for (int ks = 0; ks < 2; ++ks)
#pragma unroll
        for (int mt = 0; mt < 8; ++mt)
            a3[ks][mt] = *(const half8v*)&wt[11264 + (mt * 16 + c) * K2P + ks * 32 + qd * 8];

    const float b3r = (tid < NCO) ? b3[tid] : 0.f;
    if (tid < 64) { Lb[tid] = b1[tid]; Lb[64 + tid] = b2[tid]; }
    {   // zero G once; gather never touches cols >= 67 (MFMA pad)
        half8v z = {};
        for (int i = tid; i < (64 * K1P) / 8; i += 256) ((half8v*)G)[i] = z;
    }

    for (int qi = 0; qi < QPB; ++qi) {
        const int bs = blockIdx.x * QPB + qi;
        const int b  = bs >> 10;

        __syncthreads();   // protect G/H/nbr_s/CW reuse from previous query

        // gather: thread -> neighbor tid>>2, x-channel quarter tid&3
        {
            const int ni = tid >> 2;
            const int p4 = tid & 3;
            const int n  = (int)ball_idx[(size_t)bs * NK + ni];
            const int nn = (n < 0) ? (NP - 1) : n;    // ref: points[-1] padding
            const float* xr = x + ((size_t)b * NP + nn) * ND + p4 * 16;
#pragma unroll
            for (int i = 0; i < 4; ++i) {
                float4 v = *(const float4*)(xr + 4 * i);
                half4v h;
                h[0] = (_Float16)v.x; h[1] = (_Float16)v.y;
                h[2] = (_Float16)v.z; h[3] = (_Float16)v.w;
                *(half4v*)&G[ni * K1P + p4 * 16 + 4 * i] = h;
            }
            if (p4 == 3) nbr_s[ni] = (short)n;
            if (p4 == 0) {
                const float* pr = pos + (size_t)(b * NP + nn) * 3;
                float gx = pr[0] - new_xyz[bs * 3 + 0];
                float gy = pr[1] - new_xyz[bs * 3 + 1];
                float gz = pr[2] - new_xyz[bs * 3 + 2];
                half2v h2; h2[0] = (_Float16)gx; h2[1] = (_Float16)gy;
                *(half2v*)&G[ni * K1P + 64] = h2;
                G[ni * K1P + 66] = (_Float16)gz;
            }
        }
        __syncthreads();

        // ---- layer 1: K=96 (3 steps), out 64 ch ----
        {
            floatx4 acc[4] = {};
#pragma unroll
            for (int ks = 0; ks < 3; ++ks) {
                half8v bf = *(const half8v*)&G[myrow * K1P + ks * 32 + qd * 8];
#pragma unroll
                for (int mt = 0; mt < 4; ++mt)
                    acc[mt] = __builtin_amdgcn_mfma_f32_16x16x32_f16(a1[ks][mt], bf, acc[mt], 0, 0, 0);
            }
#pragma unroll
            for (int mt = 0; mt < 4; ++mt) {
                float4 bb = *(const float4*)&Lb[mt * 16 + qd * 4];
                half4v h;
                h[0] = (_Float16)fmaxf(acc[mt][0] + bb.x, 0.f);
                h[1] = (_Float16)fmaxf(acc[mt][1] + bb.y, 0.f);
                h[2] = (_Float16)fmaxf(acc[mt][2] + bb.z, 0.f);
                h[3] = (_Float16)fmaxf(acc[mt][3] + bb.w, 0.f);
                *(half4v*)&H1[myrow * K2P + mt * 16 + qd * 4] = h;
            }
        }
        // wave-private H rows: no block barrier needed between layers

        // ---- layer 2: K=64 (2 steps), out 64 ch ----
        {
            floatx4 acc[4] = {};
#pragma unroll
            for (int ks = 0; ks < 2; ++ks) {
                half8v bf = *(const half8v*)&H1[myrow * K2P + ks * 32 + qd * 8];
#pragma unroll
                for (int mt = 0; mt < 4; ++mt)
                    acc[mt] = __builtin_amdgcn_mfma_f32_16x16x32_f16(a2[ks][mt], bf, acc[mt], 0, 0, 0);
            }
#pragma unroll
            for (int mt = 0; mt < 4; ++mt) {
                float4 bb = *(const float4*)&Lb[64 + mt * 16 + qd * 4];
                half4v h;
                h[0] = (_Float16)fmaxf(acc[mt][0] + bb.x, 0.f);
                h[1] = (_Float16)fmaxf(acc[mt][1] + bb.y, 0.f);
                h[2] = (_Float16)fmaxf(acc[mt][2] + bb.z, 0.f);
                h[3] = (_Float16)fmaxf(acc[mt][3] + bb.w, 0.f);
                *(half4v*)&H2[myrow * K2P + mt * 16 + qd * 4] = h;
            }
        }

        // ---- layer 3 (swapped operands): C rows = neighbors, cols = out-ch ----
        {
            floatx4 acc3[8] = {};
#pragma unroll
            for (int ks = 0; ks < 2; ++ks) {
                half8v av = *(const half8v*)&H2[myrow * K2P + ks * 32 + qd * 8];
#pragma unroll
                for (int mt = 0; mt < 8; ++mt)
                    acc3[mt] = __builtin_amdgcn_mfma_f32_16x16x32_f16(av, a3[ks][mt], acc3[mt], 0, 0, 0);
            }
            const short* np4 = &nbr_s[wv * 16 + qd * 4];
            const bool v0 = np4[0] >= 0, v1 = np4[1] >= 0;
            const bool v2 = np4[2] >= 0, v3 = np4[3] >= 0;
#pragma unroll
            for (int mt = 0; mt < 8; ++mt) {
                float m = v0 ? acc3[mt][0] : -INFINITY;
                m = fmaxf(m, v1 ? acc3[mt][1] : -INFINITY);
                m = fmaxf(m, v2 ? acc3[mt][2] : -INFINITY);
                m = fmaxf(m, v3 ? acc3[mt][3] : -INFINITY);
                m = fmaxf(m, __shfl_xor(m, 16));
                m = fmaxf(m, __shfl_xor(m, 32));
                if (qd == 0) CW[wv * NCO + mt * 16 + c] = m;
            }
        }
        __syncthreads();

        if (tid < NCO) {
            float m = fmaxf(fmaxf(CW[tid], CW[NCO + tid]),
                            fmaxf(CW[2 * NCO + tid], CW[3 * NCO + tid]));
            m += b3r;                               // exact: add after max
            if (nbr_s[NK - 1] < 0) m = fmaxf(m, 0.f);  // ref's masked zeros
            out[(size_t)bs * NCO + tid] = m;
        }
    }
}

extern "C" void kernel_launch(void* const* d_in, const int* in_sizes, int n_in,
                              void* d_out, int out_size, void* d_ws, size_t ws_size,
                              hipStream_t stream) {
    const float* x   = (const float*)d_in[0];
    const float* pos = (const float*)d_in[1];
    const float* W1  = (const float*)d_in[2];
    const float* b1  = (const float*)d_in[3];
    const float* W2  = (const float*)d_in[4];
    const float* b2  = (const float*)d_in[5];
    const float* W3  = (const float*)d_in[6];
    const float* b3  = (const float*)d_in[7];

    float* out0 = (float*)d_out;                       // [B,S,128]
    float* nxyz = out0 + (size_t)NB * NS * NCO;        // [B,S,3]
    float4*   spsp = (float4*)((char*)d_ws + WS_SPS);  // sorted points, 512 KB
    short*    bidx = (short*)((char*)d_ws + WS_BIDX);  // ball idx, 1 MB
    _Float16* wtp  = (_Float16*)((char*)d_ws + WS_WT); // f16 weights, 40 KB

    wt_kernel<<<256, 64, 0, stream>>>(W1, W2, W3, wtp);
    sort_kernel<<<NB, 512, 0, stream>>>(pos, spsp);
    fps_kernel<<<NB, FPS_T, 0, stream>>>(pos, spsp, nxyz);
    ballq_kernel<<<(NB * NS) / 4, 256, 0, stream>>>(pos, nxyz, bidx);
    mlp_kernel<<<NB * NS / QPB, 256, 0, stream>>>(x, pos, b1, b2, b3,
                                                  nxyz, bidx, wtp, out0);
}

// Round 8
// 799.842 us; speedup vs baseline: 1.1828x; 1.1828x over previous
//
#include <hip/hip_runtime.h>
#include <stdint.h>

#define NB 8
#define NP 4096
#define NS 1024
#define NK 64
#define ND 64
#define NH 64
#define NCO 128

#define FPS_T 512
#define PPT (NP / FPS_T)   // 8 points per thread

// padded K strides (in halves) for conflict-free b128 LDS access
#define K1P 104            // layer1 K: 64 x-ch + 3 xyz + zeros to 96, padded to 104
#define K2P 72             // layer2/3 K: 64, padded to 72

// workspace layout (bytes)
#define WS_PROG 0          // int[8] progress flags
#define WS_WT   256        // _Float16 weights (20480 halves = 40 KB)

typedef _Float16 half8v __attribute__((ext_vector_type(8)));
typedef _Float16 half4v __attribute__((ext_vector_type(4)));
typedef _Float16 half2v __attribute__((ext_vector_type(2)));
typedef float    floatx4 __attribute__((ext_vector_type(4)));

// DPP move helper (ctrl must be compile-time constant)
template <int CTRL>
__device__ __forceinline__ float dpp_mov_f32(float x) {
    return __int_as_float(__builtin_amdgcn_update_dpp(
        0, __float_as_int(x), CTRL, 0xf, 0xf, true));
}

// ---------------- Kernel 0: weight transpose + f16 convert ----------------
__global__ __launch_bounds__(64) void wt_kernel(const float* __restrict__ W1,
                                                const float* __restrict__ W2,
                                                const float* __restrict__ W3,
                                                _Float16* __restrict__ wt)
{
    const int j = blockIdx.x;
    const int t = threadIdx.x;
    if (j < 64) {
        for (int k = t; k < K1P; k += 64) {
            float v = 0.f;
            if (k < 64)       v = W1[(3 + k) * 64 + j];
            else if (k < 67)  v = W1[(k - 64) * 64 + j];
            wt[j * K1P + k] = (_Float16)v;
        }
    } else if (j < 128) {
        const int r = j - 64;
        for (int k = t; k < K2P; k += 64) {
            float v = (k < 64) ? W2[k * 64 + r] : 0.f;
            wt[6656 + r * K2P + k] = (_Float16)v;
        }
    } else {
        const int r = j - 128;
        for (int k = t; k < K2P; k += 64) {
            float v = (k < 64) ? W3[k * 128 + r] : 0.f;
            wt[11264 + r * K2P + k] = (_Float16)v;
        }
    }
}

// ---------------- Fused kernel: fps producers + ballq/mlp consumers ----------
// Grid = 256 blocks x 512 threads. Residency: LDS 66 KB -> >=2 blk/CU;
// __launch_bounds__(512,2) caps VGPR at 256 -> >=1 blk/CU; 256 blocks always
// co-resident => spin-wait is deadlock-free without cooperative launch.
// Blocks 0..7: R6-exact fps for batch b, publishing prog[b]=s+1 (release,
// agent scope) every 16 steps. Blocks 8..255: consumer ci=blockIdx-8 handles
// batch b=ci&7, queries s = (ci>>3) + 31k. Poisoned prog (0xAAAAAAAA < 0)
// keeps consumers spinning until fps publishes.
__global__ __launch_bounds__(512, 2) void fused_kernel(
        const float* __restrict__ x, const float* __restrict__ pos,
        const float* __restrict__ b1v, const float* __restrict__ b2v,
        const float* __restrict__ b3v,
        const _Float16* __restrict__ wt,
        float* new_xyz, float* __restrict__ out, int* prog)
{
    __shared__ alignas(16) char smem[65664];
    const int tid  = threadIdx.x;
    const int lane = tid & 63;
    const int wv   = tid >> 6;

    if (blockIdx.x < NB) {
        // ================= FPS (R6-proven structure) =================
#pragma clang fp contract(off)
        const int b = blockIdx.x;
        float4* sp = (float4*)smem;                               // 64 KB
        unsigned long long* kbuf = (unsigned long long*)(smem + 65536); // [2][8]

        const float* p = pos + (size_t)b * NP * 3;
        for (int i = tid; i < NP; i += FPS_T) {
            sp[i] = make_float4(p[i * 3 + 0], p[i * 3 + 1], p[i * 3 + 2], 0.0f);
        }
        __syncthreads();

        float px[PPT], py[PPT], pz[PPT], md[PPT];
#pragma unroll
        for (int j = 0; j < PPT; ++j) {
            float4 v = sp[tid * PPT + j];
            px[j] = v.x; py[j] = v.y; pz[j] = v.z;
            md[j] = 1e10f;
        }

        int last = 0;
        if (tid == 0) {
            float4 v = sp[0];
            float* o = new_xyz + (size_t)b * NS * 3;
            o[0] = v.x; o[1] = v.y; o[2] = v.z;
        }

        int par = 0;
        for (int s = 1; s < NS; ++s) {
            const float4 lp = sp[last];
            const float lx = lp.x, ly = lp.y, lz = lp.z;

            float bv = 0.0f;
            int   bi = tid * PPT;
#pragma unroll
            for (int j = 0; j < PPT; ++j) {
                float dx = px[j] - lx;
                float dy = py[j] - ly;
                float dz = pz[j] - lz;
                float d2 = dx * dx + dy * dy + dz * dz;  // contract(off): exact
                float m  = (md[j] < d2) ? md[j] : d2;    // jnp.minimum
                md[j] = m;
                if (m > bv) { bv = m; bi = tid * PPT + j; }
            }

            float r = bv;
            r = fmaxf(r, dpp_mov_f32<0x111>(r));   // row_shr:1
            r = fmaxf(r, dpp_mov_f32<0x112>(r));   // row_shr:2
            r = fmaxf(r, dpp_mov_f32<0x114>(r));   // row_shr:4
            r = fmaxf(r, dpp_mov_f32<0x118>(r));   // row_shr:8
            r = fmaxf(r, dpp_mov_f32<0x142>(r));   // row_bcast:15
            r = fmaxf(r, dpp_mov_f32<0x143>(r));   // row_bcast:31
            const float gmax = __int_as_float(
                __builtin_amdgcn_readlane(__float_as_int(r), 63));

            unsigned long long mk = __ballot(bv == gmax);
            int wl = (int)__builtin_ctzll(mk);
            int bw = __builtin_amdgcn_readlane(bi, wl);

            if (lane == 0) {
                kbuf[par * 8 + wv] =
                    ((unsigned long long)__float_as_uint(gmax) << 32) |
                    (unsigned long long)(~(unsigned)bw);
            }
            __syncthreads();

            const ulonglong2* wb = (const ulonglong2*)(kbuf + par * 8);
            ulonglong2 q0 = wb[0], q1 = wb[1], q2 = wb[2], q3 = wb[3];
            unsigned long long a0 = (q0.y > q0.x) ? q0.y : q0.x;
            unsigned long long a1 = (q1.y > q1.x) ? q1.y : q1.x;
            unsigned long long a2 = (q2.y > q2.x) ? q2.y : q2.x;
            unsigned long long a3 = (q3.y > q3.x) ? q3.y : q3.x;
            unsigned long long b0 = (a1 > a0) ? a1 : a0;
            unsigned long long b1 = (a3 > a2) ? a3 : a2;
            unsigned long long g  = (b1 > b0) ? b1 : b0;

            last = (int)(~(unsigned)g);
            if (tid == 0) {
                float4 v = sp[last];
                float* o = new_xyz + ((size_t)b * NS + s) * 3;
                o[0] = v.x; o[1] = v.y; o[2] = v.z;
                if ((s & 15) == 15) {           // batched publish (incl. s=1023)
                    __threadfence();
                    __hip_atomic_store(prog + b, s + 1, __ATOMIC_RELEASE,
                                       __HIP_MEMORY_SCOPE_AGENT);
                }
            }
            par ^= 1;
        }
        return;
    }

    // ================= Consumer: ballq + gather + MLP + pool =================
    const int ci = blockIdx.x - NB;   // 0..247
    const int b  = ci & 7;
    const int r0 = ci >> 3;           // 0..30

    _Float16* G   = (_Float16*)smem;            // 64*K1P halves = 13312 B
    _Float16* H1  = (_Float16*)(smem + 13312);  // 64*K2P = 9216 B
    _Float16* H2  = (_Float16*)(smem + 22528);  // 9216 B
    float*    CW  = (float*)(smem + 31744);     // 4*NCO = 2048 B
    float*    Lb  = (float*)(smem + 33792);     // 128 floats = 512 B
    short*  nbr_s = (short*)(smem + 34304);     // 128 B
    float*    qv  = (float*)(smem + 34432);     // 12 B

    const int qd = lane >> 4;         // quad
    const int c  = lane & 15;         // col within MFMA tile
    const int myrow = wv * 16 + c;    // neighbor row (waves 0-3 only)

    // weight frag hoist + bias staging (waves 0-3)
    half8v a1[3][4], a2[2][4], a3[2][8];
    float b3r = 0.f;
    if (tid < 256) {
#pragma unroll
        for (int ks = 0; ks < 3; ++ks)
#pragma unroll
            for (int mt = 0; mt < 4; ++mt)
                a1[ks][mt] = *(const half8v*)&wt[(mt * 16 + c) * K1P + ks * 32 + qd * 8];
#pragma unroll
        for (int ks = 0; ks < 2; ++ks)
#pragma unroll
            for (int mt = 0; mt < 4; ++mt)
                a2[ks][mt] = *(const half8v*)&wt[6656 + (mt * 16 + c) * K2P + ks * 32 + qd * 8];
#pragma unroll
        for (int ks = 0; ks < 2; ++ks)
#pragma unroll
            for (int mt = 0; mt < 8; ++mt)
                a3[ks][mt] = *(const half8v*)&wt[11264 + (mt * 16 + c) * K2P + ks * 32 + qd * 8];
        if (tid < 64) { Lb[tid] = b1v[tid]; Lb[64 + tid] = b2v[tid]; }
        if (tid < NCO) b3r = b3v[tid];
        half8v z = {};
        for (int i = tid; i < (64 * K1P) / 8; i += 256) ((half8v*)G)[i] = z;
    }

    for (int s = r0; s < NS; s += 31) {
        const int bs = b * NS + s;

        // ---- spin until fps has published step s (prog >= s+1) ----
        int guard = 0;
        while (__hip_atomic_load(prog + b, __ATOMIC_ACQUIRE,
                                 __HIP_MEMORY_SCOPE_AGENT) < s + 1) {
            __builtin_amdgcn_s_sleep(20);
            if (++guard > (1 << 26)) break;   // escape hatch: fail loud, not hang
        }

        // ---- wave 0: ball query into LDS (proven single-wave scan) ----
        if (wv == 0) {
#pragma clang fp contract(off)
            const float* p = pos + (size_t)b * NP * 3;
            const float qx = __hip_atomic_load(new_xyz + (size_t)bs * 3 + 0,
                                               __ATOMIC_RELAXED, __HIP_MEMORY_SCOPE_AGENT);
            const float qy = __hip_atomic_load(new_xyz + (size_t)bs * 3 + 1,
                                               __ATOMIC_RELAXED, __HIP_MEMORY_SCOPE_AGENT);
            const float qz = __hip_atomic_load(new_xyz + (size_t)bs * 3 + 2,
                                               __ATOMIC_RELAXED, __HIP_MEMORY_SCOPE_AGENT);
            if (lane == 0) { qv[0] = qx; qv[1] = qy; qv[2] = qz; }
            int cnt = 0;
            for (int n0 = 0; n0 < NP; n0 += 64) {
                const int n = n0 + lane;
                float dx = qx - p[n * 3 + 0];
                float dy = qy - p[n * 3 + 1];
                float dz = qz - p[n * 3 + 2];
                float d2 = dx * dx + dy * dy + dz * dz;   // contract(off)
                bool within = d2 < 0.04f;                 // r^2, strict <
                unsigned long long m = __ballot(within);
                if (within) {
                    int slot = cnt + __popcll(m & ((1ull << lane) - 1ull));
                    if (slot < NK) nbr_s[slot] = (short)n;
                }
                cnt += (int)__popcll(m);
                if (cnt >= NK) break;
            }
            if (cnt < NK) {
                if (lane < NK - cnt) nbr_s[cnt + lane] = (short)-1;
            }
        }
        __syncthreads();   // nbr_s, qv ready

        // ---- gather (waves 0-3): thread -> neighbor tid>>2, channel quarter ----
        if (tid < 256) {
            const int ni = tid >> 2;
            const int p4 = tid & 3;
            const int n  = (int)nbr_s[ni];
            const int nn = (n < 0) ? (NP - 1) : n;    // ref: points[-1] padding
            const float* xr = x + ((size_t)b * NP + nn) * ND + p4 * 16;
#pragma unroll
            for (int i = 0; i < 4; ++i) {
                float4 v = *(const float4*)(xr + 4 * i);
                half4v h;
                h[0] = (_Float16)v.x; h[1] = (_Float16)v.y;
                h[2] = (_Float16)v.z; h[3] = (_Float16)v.w;
                *(half4v*)&G[ni * K1P + p4 * 16 + 4 * i] = h;
            }
            if (p4 == 0) {
                const float* pr = pos + (size_t)(b * NP + nn) * 3;
                float gx = pr[0] - qv[0];
                float gy = pr[1] - qv[1];
                float gz = pr[2] - qv[2];
                half2v h2; h2[0] = (_Float16)gx; h2[1] = (_Float16)gy;
                *(half2v*)&G[ni * K1P + 64] = h2;
                G[ni * K1P + 66] = (_Float16)gz;
            }
        }
        __syncthreads();

        if (tid < 256) {
            // ---- layer 1: K=96 (3 steps), out 64 ch ----
            {
                floatx4 acc[4] = {};
#pragma unroll
                for (int ks = 0; ks < 3; ++ks) {
                    half8v bf = *(const half8v*)&G[myrow * K1P + ks * 32 + qd * 8];
#pragma unroll
                    for (int mt = 0; mt < 4; ++mt)
                        acc[mt] = __builtin_amdgcn_mfma_f32_16x16x32_f16(a1[ks][mt], bf, acc[mt], 0, 0, 0);
                }
#pragma unroll
                for (int mt = 0; mt < 4; ++mt) {
                    float4 bb = *(const float4*)&Lb[mt * 16 + qd * 4];
                    half4v h;
                    h[0] = (_Float16)fmaxf(acc[mt][0] + bb.x, 0.f);
                    h[1] = (_Float16)fmaxf(acc[mt][1] + bb.y, 0.f);
                    h[2] = (_Float16)fmaxf(acc[mt][2] + bb.z, 0.f);
                    h[3] = (_Float16)fmaxf(acc[mt][3] + bb.w, 0.f);
                    *(half4v*)&H1[myrow * K2P + mt * 16 + qd * 4] = h;
                }
            }
            // ---- layer 2: K=64 (2 steps), out 64 ch ----
            {
                floatx4 acc[4] = {};
#pragma unroll
                for (int ks = 0; ks < 2; ++ks) {
                    half8v bf = *(const half8v*)&H1[myrow * K2P + ks * 32 + qd * 8];
#pragma unroll
                    for (int mt = 0; mt < 4; ++mt)
                        acc[mt] = __builtin_amdgcn_mfma_f32_16x16x32_f16(a2[ks][mt], bf, acc[mt], 0, 0, 0);
                }
#pragma unroll
                for (int mt = 0; mt < 4; ++mt) {
                    float4 bb = *(const float4*)&Lb[64 + mt * 16 + qd * 4];
                    half4v h;
                    h[0] = (_Float16)fmaxf(acc[mt][0] + bb.x, 0.f);
                    h[1] = (_Float16)fmaxf(acc[mt][1] + bb.y, 0.f);
                    h[2] = (_Float16)fmaxf(acc[mt][2] + bb.z, 0.f);
                    h[3] = (_Float16)fmaxf(acc[mt][3] + bb.w, 0.f);
                    *(half4v*)&H2[myrow * K2P + mt * 16 + qd * 4] = h;
                }
            }
            // ---- layer 3 (swapped operands): C rows = neighbors ----
            {
                floatx4 acc3[8] = {};
#pragma unroll
                for (int ks = 0; ks < 2; ++ks) {
                    half8v av = *(const half8v*)&H2[myrow * K2P + ks * 32 + qd * 8];
#pragma unroll
                    for (int mt = 0; mt < 8; ++mt)
                        acc3[mt] = __builtin_amdgcn_mfma_f32_16x16x32_f16(av, a3[ks][mt], acc3[mt], 0, 0, 0);
                }
                const short* np4 = &nbr_s[wv * 16 + qd * 4];
                const bool v0 = np4[0] >= 0, v1 = np4[1] >= 0;
                const bool v2 = np4[2] >= 0, v3 = np4[3] >= 0;
#pragma unroll
                for (int mt = 0; mt < 8; ++mt) {
                    float m = v0 ? acc3[mt][0] : -INFINITY;
                    m = fmaxf(m, v1 ? acc3[mt][1] : -INFINITY);
                    m = fmaxf(m, v2 ? acc3[mt][2] : -INFINITY);
                    m = fmaxf(m, v3 ? acc3[mt][3] : -INFINITY);
                    m = fmaxf(m, __shfl_xor(m, 16));
                    m = fmaxf(m, __shfl_xor(m, 32));
                    if (qd == 0) CW[wv * NCO + mt * 16 + c] = m;
                }
            }
        }
        __syncthreads();

        if (tid < NCO) {
            float m = fmaxf(fmaxf(CW[tid], CW[NCO + tid]),
                            fmaxf(CW[2 * NCO + tid], CW[3 * NCO + tid]));
            m += b3r;                                  // exact: add after max
            if (nbr_s[NK - 1] < 0) m = fmaxf(m, 0.f);  // ref's masked zeros
            out[(size_t)bs * NCO + tid] = m;
        }
        __syncthreads();   // protect nbr_s/G/CW before next query's ballq/gather
    }
}

extern "C" void kernel_launch(void* const* d_in, const int* in_sizes, int n_in,
                              void* d_out, int out_size, void* d_ws, size_t ws_size,
                              hipStream_t stream) {
    const float* x   = (const float*)d_in[0];
    const float* pos = (const float*)d_in[1];
    const float* W1  = (const float*)d_in[2];
    const float* b1  = (const float*)d_in[3];
    const float* W2  = (const float*)d_in[4];
    const float* b2  = (const float*)d_in[5];
    const float* W3  = (const float*)d_in[6];
    const float* b3  = (const float*)d_in[7];

    float* out0 = (float*)d_out;                        // [B,S,128]
    float* nxyz = out0 + (size_t)NB * NS * NCO;         // [B,S,3]
    int*      progp = (int*)((char*)d_ws + WS_PROG);    // 8 ints (0xAA poison < 0)
    _Float16* wtp   = (_Float16*)((char*)d_ws + WS_WT); // f16 weights, 40 KB

    wt_kernel<<<256, 64, 0, stream>>>(W1, W2, W3, wtp);
    fused_kernel<<<256, 512, 0, stream>>>(x, pos, b1, b2, b3, wtp,
                                          nxyz, out0, progp);
}

// Round 9
// 768.107 us; speedup vs baseline: 1.2316x; 1.0413x over previous
//
#include <hip/hip_runtime.h>
#include <stdint.h>

#define NB 8
#define NP 4096
#define NS 1024
#define NK 64
#define ND 64
#define NH 64
#define NCO 128

#define FPS_T 512
#define PPT (NP / FPS_T)   // 8 points per thread

// padded K strides (in halves) for conflict-free b128 LDS access
#define K1P 104            // layer1 K: 64 x-ch + 3 xyz + zeros to 96, padded to 104
#define K2P 72             // layer2/3 K: 64, padded to 72

// workspace layout (bytes)
#define WS_WIDX 0          // int[NB*NS] per-step winner index tokens (32 KB)
#define WS_WT   32768      // _Float16 weights (20480 halves = 40 KB)

typedef _Float16 half8v __attribute__((ext_vector_type(8)));
typedef _Float16 half4v __attribute__((ext_vector_type(4)));
typedef _Float16 half2v __attribute__((ext_vector_type(2)));
typedef float    floatx4 __attribute__((ext_vector_type(4)));

// DPP move helper (ctrl must be compile-time constant)
template <int CTRL>
__device__ __forceinline__ float dpp_mov_f32(float x) {
    return __int_as_float(__builtin_amdgcn_update_dpp(
        0, __float_as_int(x), CTRL, 0xf, 0xf, true));
}

// ---------------- Kernel 0: weight transpose + f16 convert ----------------
__global__ __launch_bounds__(64) void wt_kernel(const float* __restrict__ W1,
                                                const float* __restrict__ W2,
                                                const float* __restrict__ W3,
                                                _Float16* __restrict__ wt)
{
    const int j = blockIdx.x;
    const int t = threadIdx.x;
    if (j < 64) {
        for (int k = t; k < K1P; k += 64) {
            float v = 0.f;
            if (k < 64)       v = W1[(3 + k) * 64 + j];
            else if (k < 67)  v = W1[(k - 64) * 64 + j];
            wt[j * K1P + k] = (_Float16)v;
        }
    } else if (j < 128) {
        const int r = j - 64;
        for (int k = t; k < K2P; k += 64) {
            float v = (k < 64) ? W2[k * 64 + r] : 0.f;
            wt[6656 + r * K2P + k] = (_Float16)v;
        }
    } else {
        const int r = j - 128;
        for (int k = t; k < K2P; k += 64) {
            float v = (k < 64) ? W3[k * 128 + r] : 0.f;
            wt[11264 + r * K2P + k] = (_Float16)v;
        }
    }
}

// ---------------- Fused kernel: fps producers + ballq/mlp consumers ----------
// Grid = 256 blocks x 512 threads; LDS 66 KB + launch_bounds(512,2) => all
// blocks co-resident, spin-wait deadlock-free. Blocks 0..7: R6-exact fps,
// publishing the per-step WINNER INDEX as a relaxed agent-scope token
// (self-describing: no fence/release needed — the atomic value IS the data;
// 0xAA ws-poison is negative = "not ready"). Blocks 8..255: consumers read
// the token, fetch query coords straight from pos[idx] (bit-identical to
// new_xyz), then proven single-wave ballq + R6 MFMA mlp.
__global__ __launch_bounds__(512, 2) void fused_kernel(
        const float* __restrict__ x, const float* __restrict__ pos,
        const float* __restrict__ b1v, const float* __restrict__ b2v,
        const float* __restrict__ b3v,
        const _Float16* __restrict__ wt,
        float* __restrict__ new_xyz, float* __restrict__ out, int* widx)
{
    __shared__ alignas(16) char smem[65664];
    const int tid  = threadIdx.x;
    const int lane = tid & 63;
    const int wv   = tid >> 6;

    if (blockIdx.x < NB) {
        // ================= FPS (R6-proven structure + token stores) ==========
#pragma clang fp contract(off)
        const int b = blockIdx.x;
        float4* sp = (float4*)smem;                               // 64 KB
        unsigned long long* kbuf = (unsigned long long*)(smem + 65536); // [2][8]

        const float* p = pos + (size_t)b * NP * 3;
        for (int i = tid; i < NP; i += FPS_T) {
            sp[i] = make_float4(p[i * 3 + 0], p[i * 3 + 1], p[i * 3 + 2], 0.0f);
        }
        __syncthreads();

        float px[PPT], py[PPT], pz[PPT], md[PPT];
#pragma unroll
        for (int j = 0; j < PPT; ++j) {
            float4 v = sp[tid * PPT + j];
            px[j] = v.x; py[j] = v.y; pz[j] = v.z;
            md[j] = 1e10f;
        }

        int last = 0;
        if (tid == 0) {
            float4 v = sp[0];
            float* o = new_xyz + (size_t)b * NS * 3;
            o[0] = v.x; o[1] = v.y; o[2] = v.z;
            __hip_atomic_store(widx + b * NS, 0, __ATOMIC_RELAXED,
                               __HIP_MEMORY_SCOPE_AGENT);
        }

        int par = 0;
        for (int s = 1; s < NS; ++s) {
            const float4 lp = sp[last];
            const float lx = lp.x, ly = lp.y, lz = lp.z;

            float bv = 0.0f;
            int   bi = tid * PPT;
#pragma unroll
            for (int j = 0; j < PPT; ++j) {
                float dx = px[j] - lx;
                float dy = py[j] - ly;
                float dz = pz[j] - lz;
                float d2 = dx * dx + dy * dy + dz * dz;  // contract(off): exact
                float m  = (md[j] < d2) ? md[j] : d2;    // jnp.minimum
                md[j] = m;
                if (m > bv) { bv = m; bi = tid * PPT + j; }
            }

            float r = bv;
            r = fmaxf(r, dpp_mov_f32<0x111>(r));   // row_shr:1
            r = fmaxf(r, dpp_mov_f32<0x112>(r));   // row_shr:2
            r = fmaxf(r, dpp_mov_f32<0x114>(r));   // row_shr:4
            r = fmaxf(r, dpp_mov_f32<0x118>(r));   // row_shr:8
            r = fmaxf(r, dpp_mov_f32<0x142>(r));   // row_bcast:15
            r = fmaxf(r, dpp_mov_f32<0x143>(r));   // row_bcast:31
            const float gmax = __int_as_float(
                __builtin_amdgcn_readlane(__float_as_int(r), 63));

            unsigned long long mk = __ballot(bv == gmax);
            int wl = (int)__builtin_ctzll(mk);
            int bw = __builtin_amdgcn_readlane(bi, wl);

            if (lane == 0) {
                kbuf[par * 8 + wv] =
                    ((unsigned long long)__float_as_uint(gmax) << 32) |
                    (unsigned long long)(~(unsigned)bw);
            }
            __syncthreads();

            const ulonglong2* wb = (const ulonglong2*)(kbuf + par * 8);
            ulonglong2 q0 = wb[0], q1 = wb[1], q2 = wb[2], q3 = wb[3];
            unsigned long long a0 = (q0.y > q0.x) ? q0.y : q0.x;
            unsigned long long a1 = (q1.y > q1.x) ? q1.y : q1.x;
            unsigned long long a2 = (q2.y > q2.x) ? q2.y : q2.x;
            unsigned long long a3 = (q3.y > q3.x) ? q3.y : q3.x;
            unsigned long long b0 = (a1 > a0) ? a1 : a0;
            unsigned long long b1 = (a3 > a2) ? a3 : a2;
            unsigned long long g  = (b1 > b0) ? b1 : b0;

            last = (int)(~(unsigned)g);
            if (tid == 0) {
                float4 v = sp[last];
                float* o = new_xyz + ((size_t)b * NS + s) * 3;
                o[0] = v.x; o[1] = v.y; o[2] = v.z;
                // fence-free token: value IS the data (fire-and-forget)
                __hip_atomic_store(widx + b * NS + s, last, __ATOMIC_RELAXED,
                                   __HIP_MEMORY_SCOPE_AGENT);
            }
            par ^= 1;
        }
        return;
    }

    // ================= Consumer: ballq + gather + MLP + pool =================
    const int ci = blockIdx.x - NB;   // 0..247
    const int b  = ci & 7;
    const int r0 = ci >> 3;           // 0..30

    _Float16* G   = (_Float16*)smem;            // 64*K1P halves = 13312 B
    _Float16* H1  = (_Float16*)(smem + 13312);  // 64*K2P = 9216 B
    _Float16* H2  = (_Float16*)(smem + 22528);  // 9216 B
    float*    CW  = (float*)(smem + 31744);     // 4*NCO = 2048 B
    float*    Lb  = (float*)(smem + 33792);     // 128 floats = 512 B
    short*  nbr_s = (short*)(smem + 34304);     // 128 B
    float*    qv  = (float*)(smem + 34432);     // 12 B

    const int qd = lane >> 4;         // quad
    const int c  = lane & 15;         // col within MFMA tile
    const int myrow = wv * 16 + c;    // neighbor row (waves 0-3 only)

    // weight frag hoist + bias staging (waves 0-3)
    half8v a1[3][4], a2[2][4], a3[2][8];
    float b3r = 0.f;
    if (tid < 256) {
#pragma unroll
        for (int ks = 0; ks < 3; ++ks)
#pragma unroll
            for (int mt = 0; mt < 4; ++mt)
                a1[ks][mt] = *(const half8v*)&wt[(mt * 16 + c) * K1P + ks * 32 + qd * 8];
#pragma unroll
        for (int ks = 0; ks < 2; ++ks)
#pragma unroll
            for (int mt = 0; mt < 4; ++mt)
                a2[ks][mt] = *(const half8v*)&wt[6656 + (mt * 16 + c) * K2P + ks * 32 + qd * 8];
#pragma unroll
        for (int ks = 0; ks < 2; ++ks)
#pragma unroll
            for (int mt = 0; mt < 8; ++mt)
                a3[ks][mt] = *(const half8v*)&wt[11264 + (mt * 16 + c) * K2P + ks * 32 + qd * 8];
        if (tid < 64) { Lb[tid] = b1v[tid]; Lb[64 + tid] = b2v[tid]; }
        if (tid < NCO) b3r = b3v[tid];
        half8v z = {};
        for (int i = tid; i < (64 * K1P) / 8; i += 256) ((half8v*)G)[i] = z;
    }

    for (int s = r0; s < NS; s += 31) {
        const int bs = b * NS + s;

        // ---- spin on the self-describing token (poison 0xAA.. < 0) ----
        int idx = -1, guard = 0;
        for (;;) {
            idx = __hip_atomic_load(widx + bs, __ATOMIC_RELAXED,
                                    __HIP_MEMORY_SCOPE_AGENT);
            if (idx >= 0) break;
            __builtin_amdgcn_s_sleep(8);
            if (++guard > (1 << 26)) break;   // escape hatch: fail loud, not hang
        }
        const int qidx = (idx >= 0 && idx < NP) ? idx : 0;

        // ---- wave 0: ball query into LDS (query coords from pos[qidx]) ----
        if (wv == 0) {
#pragma clang fp contract(off)
            const float* p = pos + (size_t)b * NP * 3;
            const float qx = p[qidx * 3 + 0];
            const float qy = p[qidx * 3 + 1];
            const float qz = p[qidx * 3 + 2];
            if (lane == 0) { qv[0] = qx; qv[1] = qy; qv[2] = qz; }
            int cnt = 0;
            for (int n0 = 0; n0 < NP; n0 += 64) {
                const int n = n0 + lane;
                float dx = qx - p[n * 3 + 0];
                float dy = qy - p[n * 3 + 1];
                float dz = qz - p[n * 3 + 2];
                float d2 = dx * dx + dy * dy + dz * dz;   // contract(off)
                bool within = d2 < 0.04f;                 // r^2, strict <
                unsigned long long m = __ballot(within);
                if (within) {
                    int slot = cnt + __popcll(m & ((1ull << lane) - 1ull));
                    if (slot < NK) nbr_s[slot] = (short)n;
                }
                cnt += (int)__popcll(m);
                if (cnt >= NK) break;
            }
            if (cnt < NK) {
                if (lane < NK - cnt) nbr_s[cnt + lane] = (short)-1;
            }
        }
        __syncthreads();   // nbr_s, qv ready

        // ---- gather (waves 0-3): thread -> neighbor tid>>2, channel quarter ----
        if (tid < 256) {
            const int ni = tid >> 2;
            const int p4 = tid & 3;
            const int n  = (int)nbr_s[ni];
            const int nn = (n < 0) ? (NP - 1) : n;    // ref: points[-1] padding
            const float* xr = x + ((size_t)b * NP + nn) * ND + p4 * 16;
#pragma unroll
            for (int i = 0; i < 4; ++i) {
                float4 v = *(const float4*)(xr + 4 * i);
                half4v h;
                h[0] = (_Float16)v.x; h[1] = (_Float16)v.y;
                h[2] = (_Float16)v.z; h[3] = (_Float16)v.w;
                *(half4v*)&G[ni * K1P + p4 * 16 + 4 * i] = h;
            }
            if (p4 == 0) {
                const float* pr = pos + (size_t)(b * NP + nn) * 3;
                float gx = pr[0] - qv[0];
                float gy = pr[1] - qv[1];
                float gz = pr[2] - qv[2];
                half2v h2; h2[0] = (_Float16)gx; h2[1] = (_Float16)gy;
                *(half2v*)&G[ni * K1P + 64] = h2;
                G[ni * K1P + 66] = (_Float16)gz;
            }
        }
        __syncthreads();

        if (tid < 256) {
            // ---- layer 1: K=96 (3 steps), out 64 ch ----
            {
                floatx4 acc[4] = {};
#pragma unroll
                for (int ks = 0; ks < 3; ++ks) {
                    half8v bf = *(const half8v*)&G[myrow * K1P + ks * 32 + qd * 8];
#pragma unroll
                    for (int mt = 0; mt < 4; ++mt)
                        acc[mt] = __builtin_amdgcn_mfma_f32_16x16x32_f16(a1[ks][mt], bf, acc[mt], 0, 0, 0);
                }
#pragma unroll
                for (int mt = 0; mt < 4; ++mt) {
                    float4 bb = *(const float4*)&Lb[mt * 16 + qd * 4];
                    half4v h;
                    h[0] = (_Float16)fmaxf(acc[mt][0] + bb.x, 0.f);
                    h[1] = (_Float16)fmaxf(acc[mt][1] + bb.y, 0.f);
                    h[2] = (_Float16)fmaxf(acc[mt][2] + bb.z, 0.f);
                    h[3] = (_Float16)fmaxf(acc[mt][3] + bb.w, 0.f);
                    *(half4v*)&H1[myrow * K2P + mt * 16 + qd * 4] = h;
                }
            }
            // ---- layer 2: K=64 (2 steps), out 64 ch ----
            {
                floatx4 acc[4] = {};
#pragma unroll
                for (int ks = 0; ks < 2; ++ks) {
                    half8v bf = *(const half8v*)&H1[myrow * K2P + ks * 32 + qd * 8];
#pragma unroll
                    for (int mt = 0; mt < 4; ++mt)
                        acc[mt] = __builtin_amdgcn_mfma_f32_16x16x32_f16(a2[ks][mt], bf, acc[mt], 0, 0, 0);
                }
#pragma unroll
                for (int mt = 0; mt < 4; ++mt) {
                    float4 bb = *(const float4*)&Lb[64 + mt * 16 + qd * 4];
                    half4v h;
                    h[0] = (_Float16)fmaxf(acc[mt][0] + bb.x, 0.f);
                    h[1] = (_Float16)fmaxf(acc[mt][1] + bb.y, 0.f);
                    h[2] = (_Float16)fmaxf(acc[mt][2] + bb.z, 0.f);
                    h[3] = (_Float16)fmaxf(acc[mt][3] + bb.w, 0.f);
                    *(half4v*)&H2[myrow * K2P + mt * 16 + qd * 4] = h;
                }
            }
            // ---- layer 3 (swapped operands): C rows = neighbors ----
            {
                floatx4 acc3[8] = {};
#pragma unroll
                for (int ks = 0; ks < 2; ++ks) {
                    half8v av = *(const half8v*)&H2[myrow * K2P + ks * 32 + qd * 8];
#pragma unroll
                    for (int mt = 0; mt < 8; ++mt)
                        acc3[mt] = __builtin_amdgcn_mfma_f32_16x16x32_f16(av, a3[ks][mt], acc3[mt], 0, 0, 0);
                }
                const short* np4 = &nbr_s[wv * 16 + qd * 4];
                const bool v0 = np4[0] >= 0, v1 = np4[1] >= 0;
                const bool v2 = np4[2] >= 0, v3 = np4[3] >= 0;
#pragma unroll
                for (int mt = 0; mt < 8; ++mt) {
                    float m = v0 ? acc3[mt][0] : -INFINITY;
                    m = fmaxf(m, v1 ? acc3[mt][1] : -INFINITY);
                    m = fmaxf(m, v2 ? acc3[mt][2] : -INFINITY);
                    m = fmaxf(m, v3 ? acc3[mt][3] : -INFINITY);
                    m = fmaxf(m, __shfl_xor(m, 16));
                    m = fmaxf(m, __shfl_xor(m, 32));
                    if (qd == 0) CW[wv * NCO + mt * 16 + c] = m;
                }
            }
        }
        __syncthreads();

        if (tid < NCO) {
            float m = fmaxf(fmaxf(CW[tid], CW[NCO + tid]),
                            fmaxf(CW[2 * NCO + tid], CW[3 * NCO + tid]));
            m += b3r;                                  // exact: add after max
            if (nbr_s[NK - 1] < 0) m = fmaxf(m, 0.f);  // ref's masked zeros
            out[(size_t)bs * NCO + tid] = m;
        }
        __syncthreads();   // protect nbr_s/G/CW before next query's ballq/gather
    }
}

extern "C" void kernel_launch(void* const* d_in, const int* in_sizes, int n_in,
                              void* d_out, int out_size, void* d_ws, size_t ws_size,
                              hipStream_t stream) {
    const float* x   = (const float*)d_in[0];
    const float* pos = (const float*)d_in[1];
    const float* W1  = (const float*)d_in[2];
    const float* b1  = (const float*)d_in[3];
    const float* W2  = (const float*)d_in[4];
    const float* b2  = (const float*)d_in[5];
    const float* W3  = (const float*)d_in[6];
    const float* b3  = (const float*)d_in[7];

    float* out0 = (float*)d_out;                        // [B,S,128]
    float* nxyz = out0 + (size_t)NB * NS * NCO;         // [B,S,3]
    int*      widxp = (int*)((char*)d_ws + WS_WIDX);    // tokens (0xAA poison < 0)
    _Float16* wtp   = (_Float16*)((char*)d_ws + WS_WT); // f16 weights, 40 KB

    wt_kernel<<<256, 64, 0, stream>>>(W1, W2, W3, wtp);
    fused_kernel<<<256, 512, 0, stream>>>(x, pos, b1, b2, b3, wtp,
                                          nxyz, out0, widxp);
}

// Round 10
// 755.750 us; speedup vs baseline: 1.2518x; 1.0164x over previous
//
#include <hip/hip_runtime.h>
#include <stdint.h>

#define NB 8
#define NP 4096
#define NS 1024
#define NK 64
#define ND 64
#define NH 64
#define NCO 128

#define FPS_T 512
#define PPT (NP / FPS_T)   // 8 points per thread

// padded K strides (in halves) for conflict-free b128 LDS access
#define K1P 104            // layer1 K: 64 x-ch + 3 xyz + zeros to 96, padded to 104
#define K2P 72             // layer2/3 K: 64, padded to 72

// workspace layout (bytes)
#define WS_WIDX 0          // int[NB*NS] per-step winner index tokens (32 KB)
#define WS_WT   32768      // _Float16 weights (20480 halves = 40 KB)

typedef _Float16 half8v __attribute__((ext_vector_type(8)));
typedef _Float16 half4v __attribute__((ext_vector_type(4)));
typedef _Float16 half2v __attribute__((ext_vector_type(2)));
typedef float    floatx4 __attribute__((ext_vector_type(4)));

// DPP move helper (ctrl must be compile-time constant)
template <int CTRL>
__device__ __forceinline__ float dpp_mov_f32(float x) {
    return __int_as_float(__builtin_amdgcn_update_dpp(
        0, __float_as_int(x), CTRL, 0xf, 0xf, true));
}

// ---------------- Kernel 0: weight transpose + f16 convert ----------------
__global__ __launch_bounds__(64) void wt_kernel(const float* __restrict__ W1,
                                                const float* __restrict__ W2,
                                                const float* __restrict__ W3,
                                                _Float16* __restrict__ wt)
{
    const int j = blockIdx.x;
    const int t = threadIdx.x;
    if (j < 64) {
        for (int k = t; k < K1P; k += 64) {
            float v = 0.f;
            if (k < 64)       v = W1[(3 + k) * 64 + j];
            else if (k < 67)  v = W1[(k - 64) * 64 + j];
            wt[j * K1P + k] = (_Float16)v;
        }
    } else if (j < 128) {
        const int r = j - 64;
        for (int k = t; k < K2P; k += 64) {
            float v = (k < 64) ? W2[k * 64 + r] : 0.f;
            wt[6656 + r * K2P + k] = (_Float16)v;
        }
    } else {
        const int r = j - 128;
        for (int k = t; k < K2P; k += 64) {
            float v = (k < 64) ? W3[k * 128 + r] : 0.f;
            wt[11264 + r * K2P + k] = (_Float16)v;
        }
    }
}

// ---------------- Fused kernel: fps producers + ballq/mlp consumers ----------
// Grid = 256 blocks x 512 threads; LDS 66 KB + launch_bounds(512,2) => all
// blocks co-resident, spin-wait deadlock-free.
// Blocks 0..7: R6-exact fps. Producer issues NO per-step global stores:
// tokens are latched in registers (lane L of wave 0 holds winner of the step
// with s&15==L — `last` is computed redundantly by every thread) and flushed
// as ONE coalesced 16-dword store per 16 steps, so the __syncthreads vmcnt
// drain leaves the critical path. new_xyz is written by CONSUMERS from
// pos[token] (bit-identical — sp rows are verbatim pos copies; each (b,s)
// covered exactly once since r0 = s mod 31).
// Blocks 8..255: consumer ci handles batch ci&7, queries s ≡ ci>>3 (mod 31);
// spins on the self-describing token (0xAA poison < 0), then proven
// single-wave ballq + R6 MFMA mlp.
__global__ __launch_bounds__(512, 2) void fused_kernel(
        const float* __restrict__ x, const float* __restrict__ pos,
        const float* __restrict__ b1v, const float* __restrict__ b2v,
        const float* __restrict__ b3v,
        const _Float16* __restrict__ wt,
        float* __restrict__ new_xyz, float* __restrict__ out, int* widx)
{
    __shared__ alignas(16) char smem[65664];
    const int tid  = threadIdx.x;
    const int lane = tid & 63;
    const int wv   = tid >> 6;

    if (blockIdx.x < NB) {
        // ================= FPS (R6-proven structure, batched publish) ========
#pragma clang fp contract(off)
        const int b = blockIdx.x;
        float4* sp = (float4*)smem;                               // 64 KB
        unsigned long long* kbuf = (unsigned long long*)(smem + 65536); // [2][8]

        const float* p = pos + (size_t)b * NP * 3;
        for (int i = tid; i < NP; i += FPS_T) {
            sp[i] = make_float4(p[i * 3 + 0], p[i * 3 + 1], p[i * 3 + 2], 0.0f);
        }
        __syncthreads();

        float px[PPT], py[PPT], pz[PPT], md[PPT];
#pragma unroll
        for (int j = 0; j < PPT; ++j) {
            float4 v = sp[tid * PPT + j];
            px[j] = v.x; py[j] = v.y; pz[j] = v.z;
            md[j] = 1e10f;
        }

        int last = 0;
        if (tid == 0) {   // s=0 token (drains once at first barrier)
            __hip_atomic_store(widx + b * NS, 0, __ATOMIC_RELAXED,
                               __HIP_MEMORY_SCOPE_AGENT);
        }
        int tok = 0;      // per-lane latched token (wave 0 lanes 0..15 flush)

        int par = 0;
        for (int s = 1; s < NS; ++s) {
            const float4 lp = sp[last];
            const float lx = lp.x, ly = lp.y, lz = lp.z;

            float bv = 0.0f;
            int   bi = tid * PPT;
#pragma unroll
            for (int j = 0; j < PPT; ++j) {
                float dx = px[j] - lx;
                float dy = py[j] - ly;
                float dz = pz[j] - lz;
                float d2 = dx * dx + dy * dy + dz * dz;  // contract(off): exact
                float m  = (md[j] < d2) ? md[j] : d2;    // jnp.minimum
                md[j] = m;
                if (m > bv) { bv = m; bi = tid * PPT + j; }
            }

            float r = bv;
            r = fmaxf(r, dpp_mov_f32<0x111>(r));   // row_shr:1
            r = fmaxf(r, dpp_mov_f32<0x112>(r));   // row_shr:2
            r = fmaxf(r, dpp_mov_f32<0x114>(r));   // row_shr:4
            r = fmaxf(r, dpp_mov_f32<0x118>(r));   // row_shr:8
            r = fmaxf(r, dpp_mov_f32<0x142>(r));   // row_bcast:15
            r = fmaxf(r, dpp_mov_f32<0x143>(r));   // row_bcast:31
            const float gmax = __int_as_float(
                __builtin_amdgcn_readlane(__float_as_int(r), 63));

            unsigned long long mk = __ballot(bv == gmax);
            int wl = (int)__builtin_ctzll(mk);
            int bw = __builtin_amdgcn_readlane(bi, wl);

            if (lane == 0) {
                kbuf[par * 8 + wv] =
                    ((unsigned long long)__float_as_uint(gmax) << 32) |
                    (unsigned long long)(~(unsigned)bw);
            }
            __syncthreads();

            const ulonglong2* wb = (const ulonglong2*)(kbuf + par * 8);
            ulonglong2 q0 = wb[0], q1 = wb[1], q2 = wb[2], q3 = wb[3];
            unsigned long long a0 = (q0.y > q0.x) ? q0.y : q0.x;
            unsigned long long a1 = (q1.y > q1.x) ? q1.y : q1.x;
            unsigned long long a2 = (q2.y > q2.x) ? q2.y : q2.x;
            unsigned long long a3 = (q3.y > q3.x) ? q3.y : q3.x;
            unsigned long long b0 = (a1 > a0) ? a1 : a0;
            unsigned long long b1 = (a3 > a2) ? a3 : a2;
            unsigned long long g  = (b1 > b0) ? b1 : b0;

            last = (int)(~(unsigned)g);

            // latch token in the matching lane (all threads know `last`)
            if ((s & 15) == lane) tok = last;
            // flush 16 tokens as one coalesced store per 16 steps
            if ((s & 15) == 15 && wv == 0 && lane < 16) {
                __hip_atomic_store(widx + b * NS + (s - 15) + lane, tok,
                                   __ATOMIC_RELAXED, __HIP_MEMORY_SCOPE_AGENT);
            }
            par ^= 1;
        }
        return;
    }

    // ================= Consumer: ballq + gather + MLP + pool =================
    const int ci = blockIdx.x - NB;   // 0..247
    const int b  = ci & 7;
    const int r0 = ci >> 3;           // 0..30

    _Float16* G   = (_Float16*)smem;            // 64*K1P halves = 13312 B
    _Float16* H1  = (_Float16*)(smem + 13312);  // 64*K2P = 9216 B
    _Float16* H2  = (_Float16*)(smem + 22528);  // 9216 B
    float*    CW  = (float*)(smem + 31744);     // 4*NCO = 2048 B
    float*    Lb  = (float*)(smem + 33792);     // 128 floats = 512 B
    short*  nbr_s = (short*)(smem + 34304);     // 128 B
    float*    qv  = (float*)(smem + 34432);     // 12 B

    const int qd = lane >> 4;         // quad
    const int c  = lane & 15;         // col within MFMA tile
    const int myrow = wv * 16 + c;    // neighbor row (waves 0-3 only)

    // weight frag hoist + bias staging (waves 0-3)
    half8v a1[3][4], a2[2][4], a3[2][8];
    float b3r = 0.f;
    if (tid < 256) {
#pragma unroll
        for (int ks = 0; ks < 3; ++ks)
#pragma unroll
            for (int mt = 0; mt < 4; ++mt)
                a1[ks][mt] = *(const half8v*)&wt[(mt * 16 + c) * K1P + ks * 32 + qd * 8];
#pragma unroll
        for (int ks = 0; ks < 2; ++ks)
#pragma unroll
            for (int mt = 0; mt < 4; ++mt)
                a2[ks][mt] = *(const half8v*)&wt[6656 + (mt * 16 + c) * K2P + ks * 32 + qd * 8];
#pragma unroll
        for (int ks = 0; ks < 2; ++ks)
#pragma unroll
            for (int mt = 0; mt < 8; ++mt)
                a3[ks][mt] = *(const half8v*)&wt[11264 + (mt * 16 + c) * K2P + ks * 32 + qd * 8];
        if (tid < 64) { Lb[tid] = b1v[tid]; Lb[64 + tid] = b2v[tid]; }
        if (tid < NCO) b3r = b3v[tid];
        half8v z = {};
        for (int i = tid; i < (64 * K1P) / 8; i += 256) ((half8v*)G)[i] = z;
    }

    for (int s = r0; s < NS; s += 31) {
        const int bs = b * NS + s;

        // ---- spin on the self-describing token (poison 0xAA.. < 0) ----
        int idx = -1, guard = 0;
        for (;;) {
            idx = __hip_atomic_load(widx + bs, __ATOMIC_RELAXED,
                                    __HIP_MEMORY_SCOPE_AGENT);
            if (idx >= 0) break;
            __builtin_amdgcn_s_sleep(8);
            if (++guard > (1 << 26)) break;   // escape hatch: fail loud, not hang
        }
        const int qidx = (idx >= 0 && idx < NP) ? idx : 0;

        // ---- wave 0: ball query into LDS (query coords from pos[qidx]);
        //      also writes this query's new_xyz (bit-identical to producer's) --
        if (wv == 0) {
#pragma clang fp contract(off)
            const float* p = pos + (size_t)b * NP * 3;
            const float qx = p[qidx * 3 + 0];
            const float qy = p[qidx * 3 + 1];
            const float qz = p[qidx * 3 + 2];
            if (lane == 0) {
                qv[0] = qx; qv[1] = qy; qv[2] = qz;
                float* o = new_xyz + (size_t)bs * 3;
                o[0] = qx; o[1] = qy; o[2] = qz;
            }
            int cnt = 0;
            for (int n0 = 0; n0 < NP; n0 += 64) {
                const int n = n0 + lane;
                float dx = qx - p[n * 3 + 0];
                float dy = qy - p[n * 3 + 1];
                float dz = qz - p[n * 3 + 2];
                float d2 = dx * dx + dy * dy + dz * dz;   // contract(off)
                bool within = d2 < 0.04f;                 // r^2, strict <
                unsigned long long m = __ballot(within);
                if (within) {
                    int slot = cnt + __popcll(m & ((1ull << lane) - 1ull));
                    if (slot < NK) nbr_s[slot] = (short)n;
                }
                cnt += (int)__popcll(m);
                if (cnt >= NK) break;
            }
            if (cnt < NK) {
                if (lane < NK - cnt) nbr_s[cnt + lane] = (short)-1;
            }
        }
        __syncthreads();   // nbr_s, qv ready

        // ---- gather (waves 0-3): thread -> neighbor tid>>2, channel quarter ----
        if (tid < 256) {
            const int ni = tid >> 2;
            const int p4 = tid & 3;
            const int n  = (int)nbr_s[ni];
            const int nn = (n < 0) ? (NP - 1) : n;    // ref: points[-1] padding
            const float* xr = x + ((size_t)b * NP + nn) * ND + p4 * 16;
#pragma unroll
            for (int i = 0; i < 4; ++i) {
                float4 v = *(const float4*)(xr + 4 * i);
                half4v h;
                h[0] = (_Float16)v.x; h[1] = (_Float16)v.y;
                h[2] = (_Float16)v.z; h[3] = (_Float16)v.w;
                *(half4v*)&G[ni * K1P + p4 * 16 + 4 * i] = h;
            }
            if (p4 == 0) {
                const float* pr = pos + (size_t)(b * NP + nn) * 3;
                float gx = pr[0] - qv[0];
                float gy = pr[1] - qv[1];
                float gz = pr[2] - qv[2];
                half2v h2; h2[0] = (_Float16)gx; h2[1] = (_Float16)gy;
                *(half2v*)&G[ni * K1P + 64] = h2;
                G[ni * K1P + 66] = (_Float16)gz;
            }
        }
        __syncthreads();

        if (tid < 256) {
            // ---- layer 1: K=96 (3 steps), out 64 ch ----
            {
                floatx4 acc[4] = {};
#pragma unroll
                for (int ks = 0; ks < 3; ++ks) {
                    half8v bf = *(const half8v*)&G[myrow * K1P + ks * 32 + qd * 8];
#pragma unroll
                    for (int mt = 0; mt < 4; ++mt)
                        acc[mt] = __builtin_amdgcn_mfma_f32_16x16x32_f16(a1[ks][mt], bf, acc[mt], 0, 0, 0);
                }
#pragma unroll
                for (int mt = 0; mt < 4; ++mt) {
                    float4 bb = *(const float4*)&Lb[mt * 16 + qd * 4];
                    half4v h;
                    h[0] = (_Float16)fmaxf(acc[mt][0] + bb.x, 0.f);
                    h[1] = (_Float16)fmaxf(acc[mt][1] + bb.y, 0.f);
                    h[2] = (_Float16)fmaxf(acc[mt][2] + bb.z, 0.f);
                    h[3] = (_Float16)fmaxf(acc[mt][3] + bb.w, 0.f);
                    *(half4v*)&H1[myrow * K2P + mt * 16 + qd * 4] = h;
                }
            }
            // ---- layer 2: K=64 (2 steps), out 64 ch ----
            {
                floatx4 acc[4] = {};
#pragma unroll
                for (int ks = 0; ks < 2; ++ks) {
                    half8v bf = *(const half8v*)&H1[myrow * K2P + ks * 32 + qd * 8];
#pragma unroll
                    for (int mt = 0; mt < 4; ++mt)
                        acc[mt] = __builtin_amdgcn_mfma_f32_16x16x32_f16(a2[ks][mt], bf, acc[mt], 0, 0, 0);
                }
#pragma unroll
                for (int mt = 0; mt < 4; ++mt) {
                    float4 bb = *(const float4*)&Lb[64 + mt * 16 + qd * 4];
                    half4v h;
                    h[0] = (_Float16)fmaxf(acc[mt][0] + bb.x, 0.f);
                    h[1] = (_Float16)fmaxf(acc[mt][1] + bb.y, 0.f);
                    h[2] = (_Float16)fmaxf(acc[mt][2] + bb.z, 0.f);
                    h[3] = (_Float16)fmaxf(acc[mt][3] + bb.w, 0.f);
                    *(half4v*)&H2[myrow * K2P + mt * 16 + qd * 4] = h;
                }
            }
            // ---- layer 3 (swapped operands): C rows = neighbors ----
            {
                floatx4 acc3[8] = {};
#pragma unroll
                for (int ks = 0; ks < 2; ++ks) {
                    half8v av = *(const half8v*)&H2[myrow * K2P + ks * 32 + qd * 8];
#pragma unroll
                    for (int mt = 0; mt < 8; ++mt)
                        acc3[mt] = __builtin_amdgcn_mfma_f32_16x16x32_f16(av, a3[ks][mt], acc3[mt], 0, 0, 0);
                }
                const short* np4 = &nbr_s[wv * 16 + qd * 4];
                const bool v0 = np4[0] >= 0, v1 = np4[1] >= 0;
                const bool v2 = np4[2] >= 0, v3 = np4[3] >= 0;
#pragma unroll
                for (int mt = 0; mt < 8; ++mt) {
                    float m = v0 ? acc3[mt][0] : -INFINITY;
                    m = fmaxf(m, v1 ? acc3[mt][1] : -INFINITY);
                    m = fmaxf(m, v2 ? acc3[mt][2] : -INFINITY);
                    m = fmaxf(m, v3 ? acc3[mt][3] : -INFINITY);
                    m = fmaxf(m, __shfl_xor(m, 16));
                    m = fmaxf(m, __shfl_xor(m, 32));
                    if (qd == 0) CW[wv * NCO + mt * 16 + c] = m;
                }
            }
        }
        __syncthreads();

        if (tid < NCO) {
            float m = fmaxf(fmaxf(CW[tid], CW[NCO + tid]),
                            fmaxf(CW[2 * NCO + tid], CW[3 * NCO + tid]));
            m += b3r;                                  // exact: add after max
            if (nbr_s[NK - 1] < 0) m = fmaxf(m, 0.f);  // ref's masked zeros
            out[(size_t)bs * NCO + tid] = m;
        }
        __syncthreads();   // protect nbr_s/G/CW before next query's ballq/gather
    }
}

extern "C" void kernel_launch(void* const* d_in, const int* in_sizes, int n_in,
                              void* d_out, int out_size, void* d_ws, size_t ws_size,
                              hipStream_t stream) {
    const float* x   = (const float*)d_in[0];
    const float* pos = (const float*)d_in[1];
    const float* W1  = (const float*)d_in[2];
    const float* b1  = (const float*)d_in[3];
    const float* W2  = (const float*)d_in[4];
    const float* b2  = (const float*)d_in[5];
    const float* W3  = (const float*)d_in[6];
    const float* b3  = (const float*)d_in[7];

    float* out0 = (float*)d_out;                        // [B,S,128]
    float* nxyz = out0 + (size_t)NB * NS * NCO;         // [B,S,3]
    int*      widxp = (int*)((char*)d_ws + WS_WIDX);    // tokens (0xAA poison < 0)
    _Float16* wtp   = (_Float16*)((char*)d_ws + WS_WT); // f16 weights, 40 KB

    wt_kernel<<<256, 64, 0, stream>>>(W1, W2, W3, wtp);
    fused_kernel<<<256, 512, 0, stream>>>(x, pos, b1, b2, b3, wtp,
                                          nxyz, out0, widxp);
}